// Round 12
// baseline (218.921 us; speedup 1.0000x reference)
//
#include <hip/hip_runtime.h>

// Problem constants (from reference)
#define BB 8
#define LL 4096
#define DIM 1024
#define HH 16
#define MM 64
#define DH 64

// Flat sizes / output offsets (outputs concatenated, read back as f32)
constexpr long long NZ = (long long)BB * LL * DIM;   // 33554432
constexpr long long NG = (long long)BB * LL * HH;    // 524288
constexpr long long O_Z   = 0;
constexpr long long O_CRY = NZ;
constexpr long long O_NEW = NZ + NG;
constexpr long long O_CC  = NZ + 2 * NG;
constexpr long long O_FR  = NZ + 3 * NG;

// crystallised layout: int32 {0,1} (established empirically R1 vs R2).
// Journal: R8 fusion regressed (346) | R9 snap-packing regressed (267) |
// R10 snap LDS-staging WON (216; snap out of top-5). Main pinned ~160us
// across unroll-1/full/2-deep: latency-bound (VALUBusy 9%, occ 72%,
// ~3KB/wave in flight vs ~1500cy loaded latency). This round: batch-burst
// main — all 8 rows x all streams loaded before compute (~25KB/wave in
// flight, 32KB-contiguous per-stream bursts per block).

// ---------------------------------------------------------------------------
// Phase 1: streaming with batch-burst loads.
// ---------------------------------------------------------------------------
#define ROWS 8

__global__ __launch_bounds__(256) void crystal_main(
    const float4* __restrict__ zc4,
    const float4* __restrict__ zp4,
    const float4* __restrict__ fr4,
    const int*    __restrict__ ccount, // [B*L*H] int32
    const int*    __restrict__ cryst,  // [B*L*H] int32 bool
    unsigned int* __restrict__ masks,  // [gridDim*4] newly bitmasks
    float* __restrict__ out)
{
    __shared__ float lds_cry[ROWS * HH];
    __shared__ float lds_new[ROWS * HH];
    __shared__ float lds_cc [ROWS * HH];

    const int t   = threadIdx.x;
    const int h   = t >> 4;
    const int sub = t & 15;

    const long long row0  = (long long)blockIdx.x * ROWS;
    const long long base4 = row0 * (DIM / 4) + t;   // row r: base4 + r*(DIM/4)
    const long long g0    = row0 * HH + h;          // row r: g0 + r*HH

    // ---- burst loads: all rows, stream by stream (24 float4 + 16 dword
    //      outstanding per thread; 32KB contiguous per stream per block) ----
    float4 zcr[ROWS], zpr[ROWS], frr[ROWS];
    int ccr[ROWS], cvr[ROWS];
    #pragma unroll
    for (int r = 0; r < ROWS; ++r) zcr[r] = zc4[base4 + r * (DIM / 4)];
    #pragma unroll
    for (int r = 0; r < ROWS; ++r) zpr[r] = zp4[base4 + r * (DIM / 4)];
    #pragma unroll
    for (int r = 0; r < ROWS; ++r) frr[r] = fr4[base4 + r * (DIM / 4)];
    #pragma unroll
    for (int r = 0; r < ROWS; ++r) ccr[r] = ccount[g0 + r * HH];
    #pragma unroll
    for (int r = 0; r < ROWS; ++r) cvr[r] = cryst[g0 + r * HH];

    unsigned int wmask = 0u;   // newly bits for this wave: bit r*4 + (h&3)

    #pragma unroll
    for (int r = 0; r < ROWS; ++r) {
        // velocity^2: exact f32 diffs, f64 accumulate (bit-identical to R2-R10)
        double s;
        {
            double dx = (double)zcr[r].x - (double)zpr[r].x;
            double dy = (double)zcr[r].y - (double)zpr[r].y;
            double dz = (double)zcr[r].z - (double)zpr[r].z;
            double dw = (double)zcr[r].w - (double)zpr[r].w;
            s = dx * dx + dy * dy + dz * dz + dw * dw;
        }
        s += __shfl_xor(s, 1);
        s += __shfl_xor(s, 2);
        s += __shfl_xor(s, 4);
        s += __shfl_xor(s, 8);

        const bool conv = sqrt(s) < 0.01;   // velocity < TAU_CONVERGE
        const int  ccn  = conv ? ccr[r] + 1 : 0;
        const bool cry  = cvr[r] != 0;
        const bool newly   = (ccn >= 2) && !cry;
        const bool crystal = cry || newly;

        float4 zout;
        zout.x = crystal ? frr[r].x : zcr[r].x;
        zout.y = crystal ? frr[r].y : zcr[r].y;
        zout.z = crystal ? frr[r].z : zcr[r].z;
        zout.w = crystal ? frr[r].w : zcr[r].w;

        const long long idx = base4 + (long long)r * (DIM / 4);
        reinterpret_cast<float4*>(out + O_Z)[idx]  = zout;
        reinterpret_cast<float4*>(out + O_FR)[idx] = frr[r];

        if (sub == 0) {
            lds_cry[r * HH + h] = crystal ? 1.0f : 0.0f;
            lds_new[r * HH + h] = newly   ? 1.0f : 0.0f;
            lds_cc [r * HH + h] = (float)ccn;
        }

        // newly bitmask: ballot has bits only at lanes 0,16,32,48 of the wave
        const unsigned long long bal = __ballot(newly && sub == 0);
        const unsigned int b4 = (unsigned int)((bal        & 1ull)       |
                                               ((bal >> 16) & 1ull) << 1 |
                                               ((bal >> 32) & 1ull) << 2 |
                                               ((bal >> 48) & 1ull) << 3);
        wmask |= b4 << (4 * r);
    }

    if ((t & 63) == 0)
        masks[blockIdx.x * 4 + (t >> 6)] = wmask;

    __syncthreads();
    // coalesced 512B flag writes (block's g-range is contiguous: blockIdx*128)
    if (t < ROWS * HH) {
        const long long g0f = (long long)blockIdx.x * (ROWS * HH) + t;
        out[O_CRY + g0f] = lds_cry[t];
        out[O_NEW + g0f] = lds_new[t];
        out[O_CC  + g0f] = lds_cc [t];
    }
}

// ---------------------------------------------------------------------------
// Phase 2: codebook snap, LDS-staged (R10 verbatim — WON, out of top-5).
// Codebook loaded COALESCED into LDS with 65-float padded rows (conflict-
// free); distance loop LDS-only. f64 diff expression and d-order identical
// to R3-R10; 4 partial accumulators; butterfly + first-min tiebreak.
// ---------------------------------------------------------------------------
#define MB_PER_CHUNK 4                     // main-blocks per snap block
#define CHUNK_ROWS  (MB_PER_CHUNK * ROWS)  // 32
#define NCHUNKS     (BB * LL / CHUNK_ROWS) // 1024
#define CBPAD 65                           // padded floats per codebook row

__global__ __launch_bounds__(64) void crystal_snap(
    const float4* __restrict__ zc4,
    const float*  __restrict__ cb,     // [H][M][DH]
    const unsigned int* __restrict__ masks,
    float* __restrict__ out)
{
    __shared__ float cbl[MM * CBPAD];   // 16.6KB padded codebook
    __shared__ float zl[2][DH];         // double-buffered z row segment

    const int lane = threadIdx.x;              // 0..63 = code index
    const int h    = blockIdx.x / NCHUNKS;     // h-major
    const int c    = blockIdx.x % NCHUNKS;
    const int w    = h >> 2;                   // wave slot within main block
    const int h2   = h & 3;                    // bit sub-position

    // my main-block's 8-row newly mask for head h (lanes >= MB_PER_CHUNK idle)
    const int mb = c * MB_PER_CHUNK + lane;
    const unsigned int word = (lane < MB_PER_CHUNK) ? masks[mb * 4 + w] : 0u;
    unsigned int rows8 = 0u;
    #pragma unroll
    for (int r = 0; r < ROWS; ++r)
        rows8 |= ((word >> (4 * r + h2)) & 1u) << r;

    unsigned long long act = __ballot(rows8 != 0u);
    if (act == 0ull) return;   // wave-uniform; ~1.4% of blocks

    // ---- coalesced codebook load -> padded LDS ----
    const float4* cbh4 = reinterpret_cast<const float4*>(cb + (long long)h * MM * DH);
    #pragma unroll
    for (int i = 0; i < 16; ++i) {
        const int gidx = i * 64 + lane;        // float4 index within head
        const float4 v = cbh4[gidx];
        const int m  = gidx >> 4;
        const int k4 = (gidx & 15) * 4;
        float* dst = &cbl[m * CBPAD + k4];
        dst[0] = v.x; dst[1] = v.y; dst[2] = v.z; dst[3] = v.w;
    }

    // uniform work-item iterator over (lane, row) bits
    int curl = 0; unsigned int curm8 = 0u;
    auto next_bl = [&]() -> long long {
        while (curm8 == 0u) {
            if (act == 0ull) return -1;
            curl = __ffsll(act) - 1; act &= act - 1;
            curm8 = __shfl(rows8, curl);
        }
        const int r = __ffs(curm8) - 1; curm8 &= curm8 - 1;
        return (long long)(c * MB_PER_CHUNK + curl) * ROWS + r;
    };

    long long bl = next_bl();
    long long seg4 = bl * (DIM / 4) + h * (DH / 4);
    float4 zv;
    if (lane < 16) zv = zc4[seg4 + lane];      // lane k holds z chunk k

    __syncthreads();   // cbl visible
    int p = 0;

    while (bl >= 0) {
        if (lane < 16) reinterpret_cast<float4*>(zl[p])[lane] = zv;

        // prefetch next item's z
        const long long bln = next_bl();
        const long long seg4n = bln * (DIM / 4) + h * (DH / 4);
        float4 zvn;
        if (bln >= 0 && lane < 16) zvn = zc4[seg4n + lane];

        __syncthreads();   // zl[p] visible

        // distance for code `lane`: LDS-only reads; f64 diffs in the same
        // d-order as R3-R10, 4 partial accumulators
        const float* crow = &cbl[lane * CBPAD];
        const float* zrow = zl[p];
        double a0 = 0.0, a1 = 0.0, a2 = 0.0, a3 = 0.0;
        #pragma unroll
        for (int d = 0; d < DH; d += 4) {
            double q0 = (double)zrow[d + 0] - (double)crow[d + 0];
            double q1 = (double)zrow[d + 1] - (double)crow[d + 1];
            double q2 = (double)zrow[d + 2] - (double)crow[d + 2];
            double q3 = (double)zrow[d + 3] - (double)crow[d + 3];
            a0 += q0 * q0; a1 += q1 * q1; a2 += q2 * q2; a3 += q3 * q3;
        }
        double best = (a0 + a1) + (a2 + a3);
        int bidx = lane;
        #pragma unroll
        for (int m2 = 1; m2 <= 32; m2 <<= 1) {
            double ob = __shfl_xor(best, m2);
            int    oi = __shfl_xor(bidx, m2);
            if (ob < best || (ob == best && oi < bidx)) { best = ob; bidx = oi; }
        }

        if (lane < 16) {
            const float* er = &cbl[bidx * CBPAD + lane * 4];
            float4 ev;
            ev.x = er[0]; ev.y = er[1]; ev.z = er[2]; ev.w = er[3];
            reinterpret_cast<float4*>(out + O_Z)[seg4 + lane]  = ev;
            reinterpret_cast<float4*>(out + O_FR)[seg4 + lane] = ev;
        }

        p ^= 1; bl = bln; seg4 = seg4n; zv = zvn;
    }
}

extern "C" void kernel_launch(void* const* d_in, const int* in_sizes, int n_in,
                              void* d_out, int out_size, void* d_ws, size_t ws_size,
                              hipStream_t stream) {
    const float4* zc4 = (const float4*)d_in[0];
    const float4* zp4 = (const float4*)d_in[1];
    const float*  cb  = (const float*)d_in[2];
    const float4* fr4 = (const float4*)d_in[3];
    const int*    cc  = (const int*)d_in[4];
    const int*    cry = (const int*)d_in[5];
    float* out = (float*)d_out;
    unsigned int* masks = (unsigned int*)d_ws;   // 64KB of scratch

    hipLaunchKernelGGL(crystal_main, dim3((BB * LL) / ROWS), dim3(256), 0, stream,
                       zc4, zp4, fr4, cc, cry, masks, out);
    hipLaunchKernelGGL(crystal_snap, dim3(HH * NCHUNKS), dim3(64), 0, stream,
                       zc4, cb, masks, out);
}

// Round 13
// 210.569 us; speedup vs baseline: 1.0397x; 1.0397x over previous
//
#include <hip/hip_runtime.h>

// Problem constants (from reference)
#define BB 8
#define LL 4096
#define DIM 1024
#define HH 16
#define MM 64
#define DH 64

// Flat sizes / output offsets (outputs concatenated, read back as f32)
constexpr long long NZ = (long long)BB * LL * DIM;   // 33554432
constexpr long long NG = (long long)BB * LL * HH;    // 524288
constexpr long long O_Z   = 0;
constexpr long long O_CRY = NZ;
constexpr long long O_NEW = NZ + NG;
constexpr long long O_CC  = NZ + 2 * NG;
constexpr long long O_FR  = NZ + 3 * NG;

// crystallised layout: int32 {0,1} (established empirically R1 vs R2).
// Journal: R8 fusion regressed (346) | R9 snap-packing regressed (267) |
// R10 snap LDS-staging won (216) | R11 batch-burst neutral (VGPR 64, occ 38,
// still 160us) -> main is at its 5R+2W mixed-stream floor; keep R8 main.
// This round: snap's one-wave blocks had __syncthreads -> compiler emits
// s_waitcnt vmcnt(0) before s_barrier -> drains the z prefetch every item.
// One-wave blocks need NO barriers (same-wave LDS ordering via lgkmcnt).

// ---------------------------------------------------------------------------
// Phase 1: pure streaming (R8 verbatim; measured 158-167us across rounds).
// ---------------------------------------------------------------------------
#define ROWS 8

__global__ __launch_bounds__(256) void crystal_main(
    const float4* __restrict__ zc4,
    const float4* __restrict__ zp4,
    const float4* __restrict__ fr4,
    const int*    __restrict__ ccount, // [B*L*H] int32
    const int*    __restrict__ cryst,  // [B*L*H] int32 bool
    unsigned int* __restrict__ masks,  // [gridDim*4] newly bitmasks
    float* __restrict__ out)
{
    __shared__ float lds_cry[ROWS * HH];
    __shared__ float lds_new[ROWS * HH];
    __shared__ float lds_cc [ROWS * HH];

    const int t   = threadIdx.x;
    const int h   = t >> 4;
    const int sub = t & 15;

    const long long row0 = (long long)blockIdx.x * ROWS;
    long long idx = row0 * (DIM / 4) + t;
    long long g   = row0 * HH + h;

    float4 zc = zc4[idx];
    float4 zp = zp4[idx];
    float4 fr = fr4[idx];
    int    cc = ccount[g];
    int    cv = cryst[g];

    unsigned int wmask = 0u;   // newly bits for this wave: bit r*4 + (h&3)

    #pragma unroll
    for (int r = 0; r < ROWS; ++r) {
        // ---- prefetch next row (full unroll -> compiler hoists loads) ----
        const long long nidx = idx + (DIM / 4);
        const long long gn   = g + HH;
        float4 zcn, zpn, frn; int ccn_ = 0, cvn = 0;
        if (r < ROWS - 1) {
            zcn = zc4[nidx]; zpn = zp4[nidx]; frn = fr4[nidx];
            ccn_ = ccount[gn]; cvn = cryst[gn];
        }

        // velocity^2: exact f32 diffs, f64 accumulate (bit-identical to R2-R11)
        double s;
        {
            double dx = (double)zc.x - (double)zp.x;
            double dy = (double)zc.y - (double)zp.y;
            double dz = (double)zc.z - (double)zp.z;
            double dw = (double)zc.w - (double)zp.w;
            s = dx * dx + dy * dy + dz * dz + dw * dw;
        }
        s += __shfl_xor(s, 1);
        s += __shfl_xor(s, 2);
        s += __shfl_xor(s, 4);
        s += __shfl_xor(s, 8);

        const bool conv = sqrt(s) < 0.01;   // velocity < TAU_CONVERGE
        const int  ccn  = conv ? cc + 1 : 0;
        const bool cry  = cv != 0;
        const bool newly   = (ccn >= 2) && !cry;
        const bool crystal = cry || newly;

        float4 zout;
        zout.x = crystal ? fr.x : zc.x;
        zout.y = crystal ? fr.y : zc.y;
        zout.z = crystal ? fr.z : zc.z;
        zout.w = crystal ? fr.w : zc.w;

        reinterpret_cast<float4*>(out + O_Z)[idx]  = zout;
        reinterpret_cast<float4*>(out + O_FR)[idx] = fr;

        if (sub == 0) {
            lds_cry[r * HH + h] = crystal ? 1.0f : 0.0f;
            lds_new[r * HH + h] = newly   ? 1.0f : 0.0f;
            lds_cc [r * HH + h] = (float)ccn;
        }

        // newly bitmask: ballot has bits only at lanes 0,16,32,48 of the wave
        const unsigned long long bal = __ballot(newly && sub == 0);
        const unsigned int b4 = (unsigned int)((bal        & 1ull)       |
                                               ((bal >> 16) & 1ull) << 1 |
                                               ((bal >> 32) & 1ull) << 2 |
                                               ((bal >> 48) & 1ull) << 3);
        wmask |= b4 << (4 * r);

        zc = zcn; zp = zpn; fr = frn; cc = ccn_; cv = cvn;
        idx = nidx; g = gn;
    }

    if ((t & 63) == 0)
        masks[blockIdx.x * 4 + (t >> 6)] = wmask;

    __syncthreads();
    // coalesced 512B flag writes (block's g-range is contiguous: blockIdx*128)
    if (t < ROWS * HH) {
        const long long g0 = (long long)blockIdx.x * (ROWS * HH) + t;
        out[O_CRY + g0] = lds_cry[t];
        out[O_NEW + g0] = lds_new[t];
        out[O_CC  + g0] = lds_cc [t];
    }
}

// ---------------------------------------------------------------------------
// Phase 2: codebook snap, LDS-staged, BARRIER-FREE (one-wave blocks).
// R10's __syncthreads forced s_waitcnt vmcnt(0) drains (compiler semantics)
// that serialized the z prefetch. Same-wave LDS write->read ordering is
// handled by compiler-inserted lgkmcnt waits; no barrier needed.
// Decision arithmetic identical to R10/R11 (absmax 0.0723877).
// ---------------------------------------------------------------------------
#define MB_PER_CHUNK 4                     // main-blocks per snap block
#define CHUNK_ROWS  (MB_PER_CHUNK * ROWS)  // 32
#define NCHUNKS     (BB * LL / CHUNK_ROWS) // 1024
#define CBPAD 65                           // padded floats per codebook row

__global__ __launch_bounds__(64) void crystal_snap(
    const float4* __restrict__ zc4,
    const float*  __restrict__ cb,     // [H][M][DH]
    const unsigned int* __restrict__ masks,
    float* __restrict__ out)
{
    __shared__ float cbl[MM * CBPAD];   // 16.6KB padded codebook
    __shared__ float zl[2][DH];         // double-buffered z row segment

    const int lane = threadIdx.x;              // 0..63 = code index
    const int h    = blockIdx.x / NCHUNKS;     // h-major
    const int c    = blockIdx.x % NCHUNKS;
    const int w    = h >> 2;                   // wave slot within main block
    const int h2   = h & 3;                    // bit sub-position

    // my main-block's 8-row newly mask for head h (lanes >= MB_PER_CHUNK idle)
    const int mb = c * MB_PER_CHUNK + lane;
    const unsigned int word = (lane < MB_PER_CHUNK) ? masks[mb * 4 + w] : 0u;
    unsigned int rows8 = 0u;
    #pragma unroll
    for (int r = 0; r < ROWS; ++r)
        rows8 |= ((word >> (4 * r + h2)) & 1u) << r;

    unsigned long long act = __ballot(rows8 != 0u);
    if (act == 0ull) return;   // wave-uniform; ~14% of blocks

    // ---- coalesced codebook load -> padded LDS (same wave writes & reads) ----
    const float4* cbh4 = reinterpret_cast<const float4*>(cb + (long long)h * MM * DH);
    #pragma unroll
    for (int i = 0; i < 16; ++i) {
        const int gidx = i * 64 + lane;        // float4 index within head
        const float4 v = cbh4[gidx];
        const int m  = gidx >> 4;
        const int k4 = (gidx & 15) * 4;
        float* dst = &cbl[m * CBPAD + k4];
        dst[0] = v.x; dst[1] = v.y; dst[2] = v.z; dst[3] = v.w;
    }

    // uniform work-item iterator over (lane, row) bits
    int curl = 0; unsigned int curm8 = 0u;
    auto next_bl = [&]() -> long long {
        while (curm8 == 0u) {
            if (act == 0ull) return -1;
            curl = __ffsll(act) - 1; act &= act - 1;
            curm8 = __shfl(rows8, curl);
        }
        const int r = __ffs(curm8) - 1; curm8 &= curm8 - 1;
        return (long long)(c * MB_PER_CHUNK + curl) * ROWS + r;
    };

    long long bl = next_bl();
    long long seg4 = bl * (DIM / 4) + h * (DH / 4);
    float4 zv;
    if (lane < 16) zv = zc4[seg4 + lane];      // lane k holds z chunk k

    int p = 0;

    while (bl >= 0) {
        if (lane < 16) reinterpret_cast<float4*>(zl[p])[lane] = zv;

        // prefetch next item's z — stays in flight through this item's compute
        const long long bln = next_bl();
        const long long seg4n = bln * (DIM / 4) + h * (DH / 4);
        float4 zvn;
        if (bln >= 0 && lane < 16) zvn = zc4[seg4n + lane];

        // distance for code `lane`: LDS-only reads; f64 diffs in the same
        // d-order as R3-R11, 4 partial accumulators
        const float* crow = &cbl[lane * CBPAD];
        const float* zrow = zl[p];
        double a0 = 0.0, a1 = 0.0, a2 = 0.0, a3 = 0.0;
        #pragma unroll
        for (int d = 0; d < DH; d += 4) {
            double q0 = (double)zrow[d + 0] - (double)crow[d + 0];
            double q1 = (double)zrow[d + 1] - (double)crow[d + 1];
            double q2 = (double)zrow[d + 2] - (double)crow[d + 2];
            double q3 = (double)zrow[d + 3] - (double)crow[d + 3];
            a0 += q0 * q0; a1 += q1 * q1; a2 += q2 * q2; a3 += q3 * q3;
        }
        double best = (a0 + a1) + (a2 + a3);
        int bidx = lane;
        #pragma unroll
        for (int m2 = 1; m2 <= 32; m2 <<= 1) {
            double ob = __shfl_xor(best, m2);
            int    oi = __shfl_xor(bidx, m2);
            if (ob < best || (ob == best && oi < bidx)) { best = ob; bidx = oi; }
        }

        if (lane < 16) {
            const float* er = &cbl[bidx * CBPAD + lane * 4];
            float4 ev;
            ev.x = er[0]; ev.y = er[1]; ev.z = er[2]; ev.w = er[3];
            reinterpret_cast<float4*>(out + O_Z)[seg4 + lane]  = ev;
            reinterpret_cast<float4*>(out + O_FR)[seg4 + lane] = ev;
        }

        p ^= 1; bl = bln; seg4 = seg4n; zv = zvn;
    }
}

extern "C" void kernel_launch(void* const* d_in, const int* in_sizes, int n_in,
                              void* d_out, int out_size, void* d_ws, size_t ws_size,
                              hipStream_t stream) {
    const float4* zc4 = (const float4*)d_in[0];
    const float4* zp4 = (const float4*)d_in[1];
    const float*  cb  = (const float*)d_in[2];
    const float4* fr4 = (const float4*)d_in[3];
    const int*    cc  = (const int*)d_in[4];
    const int*    cry = (const int*)d_in[5];
    float* out = (float*)d_out;
    unsigned int* masks = (unsigned int*)d_ws;   // 512KB of scratch

    hipLaunchKernelGGL(crystal_main, dim3((BB * LL) / ROWS), dim3(256), 0, stream,
                       zc4, zp4, fr4, cc, cry, masks, out);
    hipLaunchKernelGGL(crystal_snap, dim3(HH * NCHUNKS), dim3(64), 0, stream,
                       zc4, cb, masks, out);
}

// Round 14
// 200.852 us; speedup vs baseline: 1.0900x; 1.0484x over previous
//
#include <hip/hip_runtime.h>

// Problem constants (from reference)
#define BB 8
#define LL 4096
#define DIM 1024
#define HH 16
#define MM 64
#define DH 64

// Flat sizes / output offsets (outputs concatenated, read back as f32)
constexpr long long NZ = (long long)BB * LL * DIM;   // 33554432
constexpr long long NG = (long long)BB * LL * HH;    // 524288
constexpr long long O_Z   = 0;
constexpr long long O_CRY = NZ;
constexpr long long O_NEW = NZ + NG;
constexpr long long O_CC  = NZ + 2 * NG;
constexpr long long O_FR  = NZ + 3 * NG;

// crystallised layout: int32 {0,1} (established empirically R1 vs R2).
// Journal: R8 fusion regressed (346) | R9 snap-packing regressed (267) |
// R10 snap LDS-staging won (216) | R11 batch-burst neutral -> main at its
// 5R+2W mixed-stream floor (~162us, keep R8 main verbatim) | R12 barrier-free
// snap won (210; snap ~45us = f64 VALU + 128 scalar LDS reads per item).
// This round: snap items go f32-from-registers with a guarded exact-f64
// fallback (gap<=1e-2, ~5% of items incl. all ties) -> decisions identical.

// ---------------------------------------------------------------------------
// Phase 1: pure streaming (R8 verbatim; 158-167us across rounds).
// ---------------------------------------------------------------------------
#define ROWS 8

__global__ __launch_bounds__(256) void crystal_main(
    const float4* __restrict__ zc4,
    const float4* __restrict__ zp4,
    const float4* __restrict__ fr4,
    const int*    __restrict__ ccount, // [B*L*H] int32
    const int*    __restrict__ cryst,  // [B*L*H] int32 bool
    unsigned int* __restrict__ masks,  // [gridDim*4] newly bitmasks
    float* __restrict__ out)
{
    __shared__ float lds_cry[ROWS * HH];
    __shared__ float lds_new[ROWS * HH];
    __shared__ float lds_cc [ROWS * HH];

    const int t   = threadIdx.x;
    const int h   = t >> 4;
    const int sub = t & 15;

    const long long row0 = (long long)blockIdx.x * ROWS;
    long long idx = row0 * (DIM / 4) + t;
    long long g   = row0 * HH + h;

    float4 zc = zc4[idx];
    float4 zp = zp4[idx];
    float4 fr = fr4[idx];
    int    cc = ccount[g];
    int    cv = cryst[g];

    unsigned int wmask = 0u;   // newly bits for this wave: bit r*4 + (h&3)

    #pragma unroll
    for (int r = 0; r < ROWS; ++r) {
        // ---- prefetch next row (full unroll -> compiler hoists loads) ----
        const long long nidx = idx + (DIM / 4);
        const long long gn   = g + HH;
        float4 zcn, zpn, frn; int ccn_ = 0, cvn = 0;
        if (r < ROWS - 1) {
            zcn = zc4[nidx]; zpn = zp4[nidx]; frn = fr4[nidx];
            ccn_ = ccount[gn]; cvn = cryst[gn];
        }

        // velocity^2: exact f32 diffs, f64 accumulate (bit-identical to R2-R12)
        double s;
        {
            double dx = (double)zc.x - (double)zp.x;
            double dy = (double)zc.y - (double)zp.y;
            double dz = (double)zc.z - (double)zp.z;
            double dw = (double)zc.w - (double)zp.w;
            s = dx * dx + dy * dy + dz * dz + dw * dw;
        }
        s += __shfl_xor(s, 1);
        s += __shfl_xor(s, 2);
        s += __shfl_xor(s, 4);
        s += __shfl_xor(s, 8);

        const bool conv = sqrt(s) < 0.01;   // velocity < TAU_CONVERGE
        const int  ccn  = conv ? cc + 1 : 0;
        const bool cry  = cv != 0;
        const bool newly   = (ccn >= 2) && !cry;
        const bool crystal = cry || newly;

        float4 zout;
        zout.x = crystal ? fr.x : zc.x;
        zout.y = crystal ? fr.y : zc.y;
        zout.z = crystal ? fr.z : zc.z;
        zout.w = crystal ? fr.w : zc.w;

        reinterpret_cast<float4*>(out + O_Z)[idx]  = zout;
        reinterpret_cast<float4*>(out + O_FR)[idx] = fr;

        if (sub == 0) {
            lds_cry[r * HH + h] = crystal ? 1.0f : 0.0f;
            lds_new[r * HH + h] = newly   ? 1.0f : 0.0f;
            lds_cc [r * HH + h] = (float)ccn;
        }

        // newly bitmask: ballot has bits only at lanes 0,16,32,48 of the wave
        const unsigned long long bal = __ballot(newly && sub == 0);
        const unsigned int b4 = (unsigned int)((bal        & 1ull)       |
                                               ((bal >> 16) & 1ull) << 1 |
                                               ((bal >> 32) & 1ull) << 2 |
                                               ((bal >> 48) & 1ull) << 3);
        wmask |= b4 << (4 * r);

        zc = zcn; zp = zpn; fr = frn; cc = ccn_; cv = cvn;
        idx = nidx; g = gn;
    }

    if ((t & 63) == 0)
        masks[blockIdx.x * 4 + (t >> 6)] = wmask;

    __syncthreads();
    // coalesced 512B flag writes (block's g-range is contiguous: blockIdx*128)
    if (t < ROWS * HH) {
        const long long g0 = (long long)blockIdx.x * (ROWS * HH) + t;
        out[O_CRY + g0] = lds_cry[t];
        out[O_NEW + g0] = lds_new[t];
        out[O_CC  + g0] = lds_cc [t];
    }
}

// ---------------------------------------------------------------------------
// Phase 2: codebook snap. Barrier-free one-wave blocks (R12), PLUS:
//  - code row in REGISTERS (f32), loaded once per block from LDS
//  - f32 distance fast path; butterfly tracks (min, argmin, 2nd-min)
//  - guarded fallback: if 2nd-min - min <= 1e-2f (covers f32 error ~1e-3 and
//    all exact ties), rerun the EXACT R12 f64 loop + f64 butterfly -> argmin
//    decisions bit-identical to R10-R12.
// ---------------------------------------------------------------------------
#define MB_PER_CHUNK 4                     // main-blocks per snap block
#define CHUNK_ROWS  (MB_PER_CHUNK * ROWS)  // 32
#define NCHUNKS     (BB * LL / CHUNK_ROWS) // 1024
#define CBPAD 68                           // 17 float4/row: b128-aligned rows

__global__ __launch_bounds__(64) void crystal_snap(
    const float4* __restrict__ zc4,
    const float*  __restrict__ cb,     // [H][M][DH]
    const unsigned int* __restrict__ masks,
    float* __restrict__ out)
{
    __shared__ float cbl[MM * CBPAD];   // 17.4KB padded codebook
    __shared__ float zl[2][DH];         // double-buffered z row segment

    const int lane = threadIdx.x;              // 0..63 = code index
    const int h    = blockIdx.x / NCHUNKS;     // h-major
    const int c    = blockIdx.x % NCHUNKS;
    const int w    = h >> 2;                   // wave slot within main block
    const int h2   = h & 3;                    // bit sub-position

    // my main-block's 8-row newly mask for head h (lanes >= MB_PER_CHUNK idle)
    const int mb = c * MB_PER_CHUNK + lane;
    const unsigned int word = (lane < MB_PER_CHUNK) ? masks[mb * 4 + w] : 0u;
    unsigned int rows8 = 0u;
    #pragma unroll
    for (int r = 0; r < ROWS; ++r)
        rows8 |= ((word >> (4 * r + h2)) & 1u) << r;

    unsigned long long act = __ballot(rows8 != 0u);
    if (act == 0ull) return;

    // uniform work-item iterator over (lane, row) bits
    int curl = 0; unsigned int curm8 = 0u;
    auto next_bl = [&]() -> long long {
        while (curm8 == 0u) {
            if (act == 0ull) return -1;
            curl = __ffsll(act) - 1; act &= act - 1;
            curm8 = __shfl(rows8, curl);
        }
        const int r = __ffs(curm8) - 1; curm8 &= curm8 - 1;
        return (long long)(c * MB_PER_CHUNK + curl) * ROWS + r;
    };

    // first item's z load issued BEFORE staging (overlaps the codebook load)
    long long bl = next_bl();
    long long seg4 = bl * (DIM / 4) + h * (DH / 4);
    float4 zv;
    if (lane < 16) zv = zc4[seg4 + lane];      // lane k holds z chunk k

    // ---- coalesced codebook load -> padded LDS (same wave writes & reads) ----
    const float4* cbh4 = reinterpret_cast<const float4*>(cb + (long long)h * MM * DH);
    #pragma unroll
    for (int i = 0; i < 16; ++i) {
        const int gidx = i * 64 + lane;        // float4 index within head
        const float4 v = cbh4[gidx];
        const int m  = gidx >> 4;
        const int k4 = (gidx & 15) * 4;
        float* dst = &cbl[m * CBPAD + k4];
        dst[0] = v.x; dst[1] = v.y; dst[2] = v.z; dst[3] = v.w;
    }

    // my code row -> registers (16 x b128 from LDS, once per block)
    float4 crw[16];
    #pragma unroll
    for (int k = 0; k < 16; ++k)
        crw[k] = *reinterpret_cast<const float4*>(&cbl[lane * CBPAD + k * 4]);

    int p = 0;

    while (bl >= 0) {
        if (lane < 16) reinterpret_cast<float4*>(zl[p])[lane] = zv;

        // prefetch next item's z — stays in flight through this item's compute
        const long long bln = next_bl();
        const long long seg4n = bln * (DIM / 4) + h * (DH / 4);
        float4 zvn;
        if (bln >= 0 && lane < 16) zvn = zc4[seg4n + lane];

        // ---- f32 fast path: distance from registers, z broadcast b128 ----
        float f0 = 0.f, f1 = 0.f, f2 = 0.f, f3 = 0.f;
        #pragma unroll
        for (int k = 0; k < 16; ++k) {
            const float4 zk = reinterpret_cast<const float4*>(zl[p])[k];
            const float q0 = zk.x - crw[k].x;
            const float q1 = zk.y - crw[k].y;
            const float q2 = zk.z - crw[k].z;
            const float q3 = zk.w - crw[k].w;
            f0 += q0 * q0; f1 += q1 * q1; f2 += q2 * q2; f3 += q3 * q3;
        }
        float b1 = (f0 + f1) + (f2 + f3);
        int   i1 = lane;
        float b2 = 3.4e38f;
        #pragma unroll
        for (int m2 = 1; m2 <= 32; m2 <<= 1) {
            const float ob1 = __shfl_xor(b1, m2);
            const int   oi1 = __shfl_xor(i1, m2);
            const float ob2 = __shfl_xor(b2, m2);
            const bool take = (ob1 < b1) || (ob1 == b1 && oi1 < i1);
            const float loser = take ? b1 : ob1;
            if (take) { b1 = ob1; i1 = oi1; }
            b2 = fminf(fminf(b2, ob2), loser);
        }
        int bidx = i1;

        // ---- guarded exact fallback (wave-uniform; ~5% of items) ----
        if (b2 - b1 <= 1e-2f) {
            const float* crow = &cbl[lane * CBPAD];
            const float* zrow = zl[p];
            double a0 = 0.0, a1 = 0.0, a2 = 0.0, a3 = 0.0;
            #pragma unroll
            for (int d = 0; d < DH; d += 4) {
                double q0 = (double)zrow[d + 0] - (double)crow[d + 0];
                double q1 = (double)zrow[d + 1] - (double)crow[d + 1];
                double q2 = (double)zrow[d + 2] - (double)crow[d + 2];
                double q3 = (double)zrow[d + 3] - (double)crow[d + 3];
                a0 += q0 * q0; a1 += q1 * q1; a2 += q2 * q2; a3 += q3 * q3;
            }
            double best = (a0 + a1) + (a2 + a3);
            int bx = lane;
            #pragma unroll
            for (int m2 = 1; m2 <= 32; m2 <<= 1) {
                double ob = __shfl_xor(best, m2);
                int    oi = __shfl_xor(bx, m2);
                if (ob < best || (ob == best && oi < bx)) { best = ob; bx = oi; }
            }
            bidx = bx;
        }

        if (lane < 16) {
            const float* er = &cbl[bidx * CBPAD + lane * 4];
            float4 ev;
            ev.x = er[0]; ev.y = er[1]; ev.z = er[2]; ev.w = er[3];
            reinterpret_cast<float4*>(out + O_Z)[seg4 + lane]  = ev;
            reinterpret_cast<float4*>(out + O_FR)[seg4 + lane] = ev;
        }

        p ^= 1; bl = bln; seg4 = seg4n; zv = zvn;
    }
}

extern "C" void kernel_launch(void* const* d_in, const int* in_sizes, int n_in,
                              void* d_out, int out_size, void* d_ws, size_t ws_size,
                              hipStream_t stream) {
    const float4* zc4 = (const float4*)d_in[0];
    const float4* zp4 = (const float4*)d_in[1];
    const float*  cb  = (const float*)d_in[2];
    const float4* fr4 = (const float4*)d_in[3];
    const int*    cc  = (const int*)d_in[4];
    const int*    cry = (const int*)d_in[5];
    float* out = (float*)d_out;
    unsigned int* masks = (unsigned int*)d_ws;   // 512KB of scratch

    hipLaunchKernelGGL(crystal_main, dim3((BB * LL) / ROWS), dim3(256), 0, stream,
                       zc4, zp4, fr4, cc, cry, masks, out);
    hipLaunchKernelGGL(crystal_snap, dim3(HH * NCHUNKS), dim3(64), 0, stream,
                       zc4, cb, masks, out);
}

// Round 15
// 198.814 us; speedup vs baseline: 1.1011x; 1.0103x over previous
//
#include <hip/hip_runtime.h>

// Problem constants (from reference)
#define BB 8
#define LL 4096
#define DIM 1024
#define HH 16
#define MM 64
#define DH 64

// Flat sizes / output offsets (outputs concatenated, read back as f32)
constexpr long long NZ = (long long)BB * LL * DIM;   // 33554432
constexpr long long NG = (long long)BB * LL * HH;    // 524288
constexpr long long O_Z   = 0;
constexpr long long O_CRY = NZ;
constexpr long long O_NEW = NZ + NG;
constexpr long long O_CC  = NZ + 2 * NG;
constexpr long long O_FR  = NZ + 3 * NG;

// crystallised layout: int32 {0,1} (established empirically R1 vs R2).
// Journal: R8 fusion regressed (346) | R9 multi-wave snap packing regressed
// (267) | R10 snap LDS-staging won (216) | R11 batch-burst neutral -> main at
// its mixed-stream floor ~160us (8 measurements, 7 schedule variants; keep R8
// main verbatim) | R12 barrier-free snap won (210) | R13 f32-fast-path +
// guarded f64 fallback won (200.9, absmax unchanged -> guard correct).
// This round: snap per-BLOCK prologue (mask read + codebook stage) ~= items
// work at MB_PER_CHUNK=4 -> double chunk to 8 (8192 blocks, ~8 items each),
// halving aggregate prologue while keeping 32 blocks/CU of TLP.

// ---------------------------------------------------------------------------
// Phase 1: pure streaming (R8 verbatim; 158-167us across rounds).
// ---------------------------------------------------------------------------
#define ROWS 8

__global__ __launch_bounds__(256) void crystal_main(
    const float4* __restrict__ zc4,
    const float4* __restrict__ zp4,
    const float4* __restrict__ fr4,
    const int*    __restrict__ ccount, // [B*L*H] int32
    const int*    __restrict__ cryst,  // [B*L*H] int32 bool
    unsigned int* __restrict__ masks,  // [gridDim*4] newly bitmasks
    float* __restrict__ out)
{
    __shared__ float lds_cry[ROWS * HH];
    __shared__ float lds_new[ROWS * HH];
    __shared__ float lds_cc [ROWS * HH];

    const int t   = threadIdx.x;
    const int h   = t >> 4;
    const int sub = t & 15;

    const long long row0 = (long long)blockIdx.x * ROWS;
    long long idx = row0 * (DIM / 4) + t;
    long long g   = row0 * HH + h;

    float4 zc = zc4[idx];
    float4 zp = zp4[idx];
    float4 fr = fr4[idx];
    int    cc = ccount[g];
    int    cv = cryst[g];

    unsigned int wmask = 0u;   // newly bits for this wave: bit r*4 + (h&3)

    #pragma unroll
    for (int r = 0; r < ROWS; ++r) {
        // ---- prefetch next row (full unroll -> compiler hoists loads) ----
        const long long nidx = idx + (DIM / 4);
        const long long gn   = g + HH;
        float4 zcn, zpn, frn; int ccn_ = 0, cvn = 0;
        if (r < ROWS - 1) {
            zcn = zc4[nidx]; zpn = zp4[nidx]; frn = fr4[nidx];
            ccn_ = ccount[gn]; cvn = cryst[gn];
        }

        // velocity^2: exact f32 diffs, f64 accumulate (bit-identical to R2-R13)
        double s;
        {
            double dx = (double)zc.x - (double)zp.x;
            double dy = (double)zc.y - (double)zp.y;
            double dz = (double)zc.z - (double)zp.z;
            double dw = (double)zc.w - (double)zp.w;
            s = dx * dx + dy * dy + dz * dz + dw * dw;
        }
        s += __shfl_xor(s, 1);
        s += __shfl_xor(s, 2);
        s += __shfl_xor(s, 4);
        s += __shfl_xor(s, 8);

        const bool conv = sqrt(s) < 0.01;   // velocity < TAU_CONVERGE
        const int  ccn  = conv ? cc + 1 : 0;
        const bool cry  = cv != 0;
        const bool newly   = (ccn >= 2) && !cry;
        const bool crystal = cry || newly;

        float4 zout;
        zout.x = crystal ? fr.x : zc.x;
        zout.y = crystal ? fr.y : zc.y;
        zout.z = crystal ? fr.z : zc.z;
        zout.w = crystal ? fr.w : zc.w;

        reinterpret_cast<float4*>(out + O_Z)[idx]  = zout;
        reinterpret_cast<float4*>(out + O_FR)[idx] = fr;

        if (sub == 0) {
            lds_cry[r * HH + h] = crystal ? 1.0f : 0.0f;
            lds_new[r * HH + h] = newly   ? 1.0f : 0.0f;
            lds_cc [r * HH + h] = (float)ccn;
        }

        // newly bitmask: ballot has bits only at lanes 0,16,32,48 of the wave
        const unsigned long long bal = __ballot(newly && sub == 0);
        const unsigned int b4 = (unsigned int)((bal        & 1ull)       |
                                               ((bal >> 16) & 1ull) << 1 |
                                               ((bal >> 32) & 1ull) << 2 |
                                               ((bal >> 48) & 1ull) << 3);
        wmask |= b4 << (4 * r);

        zc = zcn; zp = zpn; fr = frn; cc = ccn_; cv = cvn;
        idx = nidx; g = gn;
    }

    if ((t & 63) == 0)
        masks[blockIdx.x * 4 + (t >> 6)] = wmask;

    __syncthreads();
    // coalesced 512B flag writes (block's g-range is contiguous: blockIdx*128)
    if (t < ROWS * HH) {
        const long long g0 = (long long)blockIdx.x * (ROWS * HH) + t;
        out[O_CRY + g0] = lds_cry[t];
        out[O_NEW + g0] = lds_new[t];
        out[O_CC  + g0] = lds_cc [t];
    }
}

// ---------------------------------------------------------------------------
// Phase 2: codebook snap. Barrier-free one-wave blocks (R12), code row in
// registers + f32 fast path + guarded exact-f64 fallback (R13), and
// MB_PER_CHUNK=8 (this round): 8192 blocks, ~8 items each -> per-block
// prologue amortized 2x, still 32 blocks/CU of TLP.
// ---------------------------------------------------------------------------
#define MB_PER_CHUNK 8                     // main-blocks per snap block
#define CHUNK_ROWS  (MB_PER_CHUNK * ROWS)  // 64
#define NCHUNKS     (BB * LL / CHUNK_ROWS) // 512
#define CBPAD 68                           // 17 float4/row: b128-aligned rows

__global__ __launch_bounds__(64) void crystal_snap(
    const float4* __restrict__ zc4,
    const float*  __restrict__ cb,     // [H][M][DH]
    const unsigned int* __restrict__ masks,
    float* __restrict__ out)
{
    __shared__ float cbl[MM * CBPAD];   // 17.4KB padded codebook
    __shared__ float zl[2][DH];         // double-buffered z row segment

    const int lane = threadIdx.x;              // 0..63 = code index
    const int h    = blockIdx.x / NCHUNKS;     // h-major
    const int c    = blockIdx.x % NCHUNKS;
    const int w    = h >> 2;                   // wave slot within main block
    const int h2   = h & 3;                    // bit sub-position

    // my main-block's 8-row newly mask for head h (lanes >= MB_PER_CHUNK idle)
    const int mb = c * MB_PER_CHUNK + lane;
    const unsigned int word = (lane < MB_PER_CHUNK) ? masks[mb * 4 + w] : 0u;
    unsigned int rows8 = 0u;
    #pragma unroll
    for (int r = 0; r < ROWS; ++r)
        rows8 |= ((word >> (4 * r + h2)) & 1u) << r;

    unsigned long long act = __ballot(rows8 != 0u);
    if (act == 0ull) return;

    // uniform work-item iterator over (lane, row) bits
    int curl = 0; unsigned int curm8 = 0u;
    auto next_bl = [&]() -> long long {
        while (curm8 == 0u) {
            if (act == 0ull) return -1;
            curl = __ffsll(act) - 1; act &= act - 1;
            curm8 = __shfl(rows8, curl);
        }
        const int r = __ffs(curm8) - 1; curm8 &= curm8 - 1;
        return (long long)(c * MB_PER_CHUNK + curl) * ROWS + r;
    };

    // first item's z load issued BEFORE staging (overlaps the codebook load)
    long long bl = next_bl();
    long long seg4 = bl * (DIM / 4) + h * (DH / 4);
    float4 zv;
    if (lane < 16) zv = zc4[seg4 + lane];      // lane k holds z chunk k

    // ---- coalesced codebook load -> padded LDS (same wave writes & reads) ----
    const float4* cbh4 = reinterpret_cast<const float4*>(cb + (long long)h * MM * DH);
    #pragma unroll
    for (int i = 0; i < 16; ++i) {
        const int gidx = i * 64 + lane;        // float4 index within head
        const float4 v = cbh4[gidx];
        const int m  = gidx >> 4;
        const int k4 = (gidx & 15) * 4;
        float* dst = &cbl[m * CBPAD + k4];
        dst[0] = v.x; dst[1] = v.y; dst[2] = v.z; dst[3] = v.w;
    }

    // my code row -> registers (16 x b128 from LDS, once per block)
    float4 crw[16];
    #pragma unroll
    for (int k = 0; k < 16; ++k)
        crw[k] = *reinterpret_cast<const float4*>(&cbl[lane * CBPAD + k * 4]);

    int p = 0;

    while (bl >= 0) {
        if (lane < 16) reinterpret_cast<float4*>(zl[p])[lane] = zv;

        // prefetch next item's z — stays in flight through this item's compute
        const long long bln = next_bl();
        const long long seg4n = bln * (DIM / 4) + h * (DH / 4);
        float4 zvn;
        if (bln >= 0 && lane < 16) zvn = zc4[seg4n + lane];

        // ---- f32 fast path: distance from registers, z broadcast b128 ----
        float f0 = 0.f, f1 = 0.f, f2 = 0.f, f3 = 0.f;
        #pragma unroll
        for (int k = 0; k < 16; ++k) {
            const float4 zk = reinterpret_cast<const float4*>(zl[p])[k];
            const float q0 = zk.x - crw[k].x;
            const float q1 = zk.y - crw[k].y;
            const float q2 = zk.z - crw[k].z;
            const float q3 = zk.w - crw[k].w;
            f0 += q0 * q0; f1 += q1 * q1; f2 += q2 * q2; f3 += q3 * q3;
        }
        float b1 = (f0 + f1) + (f2 + f3);
        int   i1 = lane;
        float b2 = 3.4e38f;
        #pragma unroll
        for (int m2 = 1; m2 <= 32; m2 <<= 1) {
            const float ob1 = __shfl_xor(b1, m2);
            const int   oi1 = __shfl_xor(i1, m2);
            const float ob2 = __shfl_xor(b2, m2);
            const bool take = (ob1 < b1) || (ob1 == b1 && oi1 < i1);
            const float loser = take ? b1 : ob1;
            if (take) { b1 = ob1; i1 = oi1; }
            b2 = fminf(fminf(b2, ob2), loser);
        }
        int bidx = i1;

        // ---- guarded exact fallback (wave-uniform; ~5% of items) ----
        if (b2 - b1 <= 1e-2f) {
            const float* crow = &cbl[lane * CBPAD];
            const float* zrow = zl[p];
            double a0 = 0.0, a1 = 0.0, a2 = 0.0, a3 = 0.0;
            #pragma unroll
            for (int d = 0; d < DH; d += 4) {
                double q0 = (double)zrow[d + 0] - (double)crow[d + 0];
                double q1 = (double)zrow[d + 1] - (double)crow[d + 1];
                double q2 = (double)zrow[d + 2] - (double)crow[d + 2];
                double q3 = (double)zrow[d + 3] - (double)crow[d + 3];
                a0 += q0 * q0; a1 += q1 * q1; a2 += q2 * q2; a3 += q3 * q3;
            }
            double best = (a0 + a1) + (a2 + a3);
            int bx = lane;
            #pragma unroll
            for (int m2 = 1; m2 <= 32; m2 <<= 1) {
                double ob = __shfl_xor(best, m2);
                int    oi = __shfl_xor(bx, m2);
                if (ob < best || (ob == best && oi < bx)) { best = ob; bx = oi; }
            }
            bidx = bx;
        }

        if (lane < 16) {
            const float* er = &cbl[bidx * CBPAD + lane * 4];
            float4 ev;
            ev.x = er[0]; ev.y = er[1]; ev.z = er[2]; ev.w = er[3];
            reinterpret_cast<float4*>(out + O_Z)[seg4 + lane]  = ev;
            reinterpret_cast<float4*>(out + O_FR)[seg4 + lane] = ev;
        }

        p ^= 1; bl = bln; seg4 = seg4n; zv = zvn;
    }
}

extern "C" void kernel_launch(void* const* d_in, const int* in_sizes, int n_in,
                              void* d_out, int out_size, void* d_ws, size_t ws_size,
                              hipStream_t stream) {
    const float4* zc4 = (const float4*)d_in[0];
    const float4* zp4 = (const float4*)d_in[1];
    const float*  cb  = (const float*)d_in[2];
    const float4* fr4 = (const float4*)d_in[3];
    const int*    cc  = (const int*)d_in[4];
    const int*    cry = (const int*)d_in[5];
    float* out = (float*)d_out;
    unsigned int* masks = (unsigned int*)d_ws;   // 64KB of scratch

    hipLaunchKernelGGL(crystal_main, dim3((BB * LL) / ROWS), dim3(256), 0, stream,
                       zc4, zp4, fr4, cc, cry, masks, out);
    hipLaunchKernelGGL(crystal_snap, dim3(HH * NCHUNKS), dim3(64), 0, stream,
                       zc4, cb, masks, out);
}